// Round 9
// baseline (149.948 us; speedup 1.0000x reference)
//
#include <hip/hip_runtime.h>

// BLAMem: truncated tensor-algebra (depth 4, C=8) log-signature memory.
// 7 stream-ordered dispatches. Lessons: no cross-block flag sync (r6), no
// device-scope atomic reductions (r7), stride-9 padded LDS rows (r7), and
// maximize block count — 256-block kernels run 1 wave/SIMD with zero latency
// hiding (r8). Chunk-local sigs are independent (1024-way parallel); only the
// group product is serial, and it's now 3 short ta_muls.

#define MEM   4680   // 8 + 64 + 512 + 4096 (unpadded global layout)
#define NG    32     // groups per batch
#define TLEN  2048
// Padded LDS signature layout: L1 [0,8), L2 [8,72), L3 rows ij*9+k at 72 (576),
// L4 rows ijk*9+l at 648 (4608). Total 5256 floats.
#define P3OFF 72
#define P4OFF 648
#define SIGSZ 5256

// padded-LDS <- unpadded-global signature row (coalesced reads, conflict-free writes)
__device__ __forceinline__ void load_padded(float* dst, const float* __restrict__ src, int tid) {
    if (tid < 72) dst[tid] = src[tid];
    for (int e = tid; e < 512; e += 256) dst[P3OFF + (e >> 3) * 9 + (e & 7)] = src[72 + e];
    for (int e = tid; e < 4096; e += 256) dst[P4OFF + (e >> 3) * 9 + (e & 7)] = src[584 + e];
}

// ------------------------------------------------ kernel 1: chunk-local sigs (grid 1024)
// block = (b,n). Closed-form 16-step Chen recurrence, registers -> global. No fold.
__global__ __launch_bounds__(256) void chunk_sig_kernel(const float* __restrict__ x,
                                                        float* __restrict__ Q) {
    int blk = blockIdx.x;
    int b = blk >> 7, n = blk & 127;
    int tid = threadIdx.x;
    __shared__ float dch[128];
    if (tid < 128) {
        int s = tid >> 3, c = tid & 7;
        int t = n * 16 + s;
        float v;
        if (c < 7) {
            float cur  = x[(b * TLEN + t) * 7 + c];
            float prev = (t > 0) ? x[(b * TLEN + t - 1) * 7 + c] : 0.f;
            v = cur - prev;
        } else v = (t > 0) ? (1.f / 2047.f) : 0.f;
        dch[tid] = v;
    }
    __syncthreads();

    const int i1 = tid >> 6, j1 = (tid >> 3) & 7, k1 = tid & 7;
    const int row1 = tid >> 3, row2 = row1 + 32;
    const int pos2 = tid + 256, i2 = pos2 >> 6;
    float p1a = 0.f, l2a = 0.f, l3a = 0.f, p1b = 0.f, l2b = 0.f, l3b = 0.f;
    float Sa[8], Sb[8];
#pragma unroll
    for (int l = 0; l < 8; l++) { Sa[l] = 0.f; Sb[l] = 0.f; }
#pragma unroll
    for (int t = 0; t < 16; t++) {
        const float* dr = &dch[t * 8];
        float di1 = dr[i1], di2 = dr[i2], dj = dr[j1], dk = dr[k1];
        float ga = l3a + dk * (l2a * 0.5f + dj * (p1a * (1.f/6.f) + di1 * (1.f/24.f)));
        float gb = l3b + dk * (l2b * 0.5f + dj * (p1b * (1.f/6.f) + di2 * (1.f/24.f)));
#pragma unroll
        for (int l = 0; l < 8; l++) { float dv = dr[l]; Sa[l] += ga * dv; Sb[l] += gb * dv; }
        l3a += dk * (l2a + dj * (p1a * 0.5f + di1 * (1.f/6.f)));
        l3b += dk * (l2b + dj * (p1b * 0.5f + di2 * (1.f/6.f)));
        l2a += (p1a + di1 * 0.5f) * dj;
        l2b += (p1b + di2 * 0.5f) * dj;
        p1a += di1; p1b += di2;
    }
    size_t base = (size_t)blk * MEM;
    float4* d1 = (float4*)(Q + base + 584 + tid * 8);
    d1[0] = make_float4(Sa[0], Sa[1], Sa[2], Sa[3]);
    d1[1] = make_float4(Sa[4], Sa[5], Sa[6], Sa[7]);
    float4* d2 = (float4*)(Q + base + 584 + pos2 * 8);
    d2[0] = make_float4(Sb[0], Sb[1], Sb[2], Sb[3]);
    d2[1] = make_float4(Sb[4], Sb[5], Sb[6], Sb[7]);
    Q[base + 72 + tid] = l3a;
    Q[base + 72 + pos2] = l3b;
    if (k1 == 0) { Q[base + 8 + row1] = l2a; Q[base + 8 + row2] = l2b; }
    if ((tid & 63) == 0) { Q[base + i1] = p1a; Q[base + i2] = p1b; }
}

// ------------------------------------------------ kernel 2: in-place group fold (grid 256)
// block = (b,g): rows 4g..4g+3 of Q become within-group cumulatives (row 4g+3 = total).
__global__ __launch_bounds__(256) void group_fold_kernel(float* __restrict__ Q) {
    int blk = blockIdx.x;
    int tid = threadIdx.x;
    __shared__ __attribute__((aligned(16))) float sA[SIGSZ];
    __shared__ __attribute__((aligned(16))) float sB[SIGSZ];

    const int i1 = tid >> 6, k1 = tid & 7;
    const int row1 = tid >> 3, row2 = row1 + 32;
    const int jk = tid & 63;
    const int pos2 = tid + 256, i2 = pos2 >> 6;

    size_t base0 = (size_t)blk * 4 * MEM;
    load_padded(sA, Q + base0, tid);

    for (int c = 1; c < 4; c++) {
        load_padded(sB, Q + base0 + (size_t)c * MEM, tid);
        __syncthreads();
        float a1 = sA[i1], a2 = sA[8 + row1], a3 = sA[P3OFF + row1 * 9 + k1];
        float c1_ = sA[i2], c2_ = sA[8 + row2], c3_ = sA[P3OFF + row2 * 9 + k1];
        const float* b3p = &sB[P3OFF + jk * 9];
        const float* b2p = &sB[8 + k1 * 8];
        float n4a[8], n4b[8];
#pragma unroll
        for (int l = 0; l < 8; l++) {
            float v3 = b3p[l], v2 = b2p[l], v1 = sB[l];
            n4a[l] = sA[P4OFF + tid * 9 + l]  + sB[P4OFF + tid * 9 + l]  + a1 * v3 + a2 * v2 + a3 * v1;
            n4b[l] = sA[P4OFF + pos2 * 9 + l] + sB[P4OFF + pos2 * 9 + l] + c1_ * v3 + c2_ * v2 + c3_ * v1;
        }
        float n3a = a3 + sB[P3OFF + row1 * 9 + k1] + a1 * sB[8 + jk] + a2 * sB[k1];
        float n3b = c3_ + sB[P3OFF + row2 * 9 + k1] + c1_ * sB[8 + jk] + c2_ * sB[k1];
        float n2v = 0.f, n1v = 0.f;
        if (tid < 64) n2v = sA[8 + tid] + sB[8 + tid] + sA[tid >> 3] * sB[tid & 7];
        if (tid < 8)  n1v = sA[tid] + sB[tid];
        __syncthreads();
        size_t bc = base0 + (size_t)c * MEM;
#pragma unroll
        for (int l = 0; l < 8; l++) { sA[P4OFF + tid * 9 + l] = n4a[l]; sA[P4OFF + pos2 * 9 + l] = n4b[l]; }
        float4* d1 = (float4*)(Q + bc + 584 + tid * 8);
        d1[0] = make_float4(n4a[0], n4a[1], n4a[2], n4a[3]);
        d1[1] = make_float4(n4a[4], n4a[5], n4a[6], n4a[7]);
        float4* d2 = (float4*)(Q + bc + 584 + pos2 * 8);
        d2[0] = make_float4(n4b[0], n4b[1], n4b[2], n4b[3]);
        d2[1] = make_float4(n4b[4], n4b[5], n4b[6], n4b[7]);
        sA[P3OFF + row1 * 9 + k1] = n3a; Q[bc + 72 + tid] = n3a;
        sA[P3OFF + row2 * 9 + k1] = n3b; Q[bc + 72 + pos2] = n3b;
        if (tid < 64) { sA[8 + tid] = n2v; Q[bc + 8 + tid] = n2v; }
        if (tid < 8)  { sA[tid] = n1v;    Q[bc + tid] = n1v; }
    }
}

// ------------------------------------------------ kernel 3: cascade scan totals -> P
// grid = 8 b x 16 slices. Group totals live at Q rows (b*128 + 4g+3).
__global__ __launch_bounds__(256) void scan_fused_kernel(const float* __restrict__ Q,
                                                         float* __restrict__ P) {
    int bx = blockIdx.x;
    int b = bx >> 4, s = bx & 15;
    int tid = threadIdx.x;

    __shared__ float st1[NG][8];
    __shared__ float st2[NG][64];
    __shared__ float st3[NG][32];
    __shared__ float sp1[NG][8];
    __shared__ float sp2[NG][64];
    __shared__ float sp3[NG][32];

    int bBase = b * NG;
    size_t qb = (size_t)b * 128;
    {
        int g = tid >> 3, i = tid & 7;
        st1[g][i] = Q[(qb + g * 4 + 3) * MEM + i];
    }
    for (int m = tid; m < NG * 64; m += 256) {
        int g = m >> 6, e = m & 63;
        st2[g][e] = Q[(qb + g * 4 + 3) * MEM + 8 + e];
    }
    for (int m = tid; m < NG * 32; m += 256) {
        int g = m >> 5, e = m & 31;
        st3[g][e] = Q[(qb + g * 4 + 3) * MEM + 72 + s * 32 + e];
    }
    __syncthreads();

    if (tid < 64) {
        int i = tid >> 3, k = tid & 7;
        float p1acc = 0.f, p2acc = 0.f;
        for (int g = 0; g < NG; g++) {
            sp2[g][tid] = p2acc;
            if (k == 0) sp1[g][i] = p1acc;
            if (s == 0) {
                size_t prow = (size_t)(bBase + g) * MEM;
                P[prow + 8 + tid] = p2acc;
                if (k == 0) P[prow + i] = p1acc;
            }
            p2acc += st2[g][tid] + p1acc * st1[g][k];
            p1acc += st1[g][i];
        }
    }
    __syncthreads();
    if (tid < 32) {
        int ijk = s * 32 + tid;
        int i = ijk >> 6, jk = ijk & 63, ij = ijk >> 3, k = ijk & 7;
        float acc3 = 0.f;
        for (int g = 0; g < NG; g++) {
            sp3[g][tid] = acc3;
            P[(size_t)(bBase + g) * MEM + 72 + ijk] = acc3;
            acc3 += st3[g][tid] + sp1[g][i] * st2[g][jk] + sp2[g][ij] * st1[g][k];
        }
    }
    __syncthreads();
    {
        int m = s * 256 + tid;
        int i = m >> 9, jkl = m & 511, ij = m >> 6, kl = m & 63, l = m & 7;
        int p3loc = tid >> 3;
        float acc4 = 0.f;
#pragma unroll 4
        for (int g = 0; g < NG; g++) {
            size_t trow = (qb + g * 4 + 3) * MEM;
            P[(size_t)(bBase + g) * MEM + 584 + m] = acc4;
            acc4 += Q[trow + 584 + m]
                  + sp1[g][i] * Q[trow + 72 + jkl]
                  + sp2[g][ij] * st2[g][kl]
                  + sp3[g][p3loc] * st1[g][l];
        }
    }
}

// ------------------------------------------------ kernel 4: apply prefix + log (grid 1024)
// block = (b,n): R = P[b, n/4] (x) Q[b,n]; part[b,n] = ta_log(R).
__global__ __launch_bounds__(256) void apply_log_kernel(const float* __restrict__ Q,
                                                        const float* __restrict__ P,
                                                        float* __restrict__ part) {
    int blk = blockIdx.x;
    int b = blk >> 7, n = blk & 127, g = n >> 2;
    int tid = threadIdx.x;
    __shared__ __attribute__((aligned(16))) float sP[SIGSZ];
    __shared__ __attribute__((aligned(16))) float sB[SIGSZ];
    __shared__ __attribute__((aligned(16))) float sR[648];
    __shared__ __attribute__((aligned(16))) float sQ23[576];

    load_padded(sP, P + (size_t)(b * NG + g) * MEM, tid);
    load_padded(sB, Q + (size_t)blk * MEM, tid);
    __syncthreads();

    const int i1 = tid >> 6, j1 = (tid >> 3) & 7, k1 = tid & 7;
    const int row1 = tid >> 3, row2 = row1 + 32;
    const int jk = tid & 63;
    const int pos2 = tid + 256, i2 = pos2 >> 6;

    float a1 = sP[i1], a2 = sP[8 + row1], a3 = sP[P3OFF + row1 * 9 + k1];
    float c1_ = sP[i2], c2_ = sP[8 + row2], c3_ = sP[P3OFF + row2 * 9 + k1];
    const float* b3p = &sB[P3OFF + jk * 9];
    const float* b2p = &sB[8 + k1 * 8];
    float R4a[8], R4b[8];
#pragma unroll
    for (int l = 0; l < 8; l++) {
        float v3 = b3p[l], v2 = b2p[l], v1 = sB[l];
        R4a[l] = sP[P4OFF + tid * 9 + l]  + sB[P4OFF + tid * 9 + l]  + a1 * v3 + a2 * v2 + a3 * v1;
        R4b[l] = sP[P4OFF + pos2 * 9 + l] + sB[P4OFF + pos2 * 9 + l] + c1_ * v3 + c2_ * v2 + c3_ * v1;
    }
    float R3a = a3 + sB[P3OFF + row1 * 9 + k1] + a1 * sB[8 + jk] + a2 * sB[k1];
    float R3b = c3_ + sB[P3OFF + row2 * 9 + k1] + c1_ * sB[8 + jk] + c2_ * sB[k1];
    float R2v = 0.f, R1v = 0.f;
    if (tid < 64) R2v = sP[8 + tid] + sB[8 + tid] + sP[tid >> 3] * sB[tid & 7];
    if (tid < 8)  R1v = sP[tid] + sB[tid];

    sR[P3OFF + row1 * 9 + k1] = R3a;
    sR[P3OFF + row2 * 9 + k1] = R3b;
    if (tid < 64) sR[8 + tid] = R2v;
    if (tid < 8)  sR[tid] = R1v;
    __syncthreads();

    float q23a = sR[i1] * sR[8 + jk] + sR[8 + row1] * sR[k1];
    float q23b = sR[i2] * sR[8 + jk] + sR[8 + row2] * sR[k1];
    sQ23[row1 * 9 + k1] = q23a;
    sQ23[row2 * 9 + k1] = q23b;
    __syncthreads();

    size_t base = (size_t)blk * MEM;
    {
        float s1ia = sR[i1], s1ib = sR[i2], s1j = sR[j1], s1k = sR[k1];
        float s2ija = sR[8 + row1], s2ijb = sR[8 + row2];
        const float* r3p = &sR[P3OFF + jk * 9];
        const float* r2p = &sR[8 + k1 * 8];
        const float* q23p = &sQ23[jk * 9];
        float out4a[8], out4b[8];
#pragma unroll
        for (int l = 0; l < 8; l++) {
            float s1l = sR[l];
            float p22 = s1k * s1l;
            float p24a = s1ia * r3p[l] + s2ija * r2p[l] + R3a * s1l;
            float p24b = s1ib * r3p[l] + s2ijb * r2p[l] + R3b * s1l;
            float p34a = s1ia * q23p[l] + s2ija * p22;
            float p34b = s1ib * q23p[l] + s2ijb * p22;
            float p44a = s1ia * s1j * p22;
            float p44b = s1ib * s1j * p22;
            out4a[l] = R4a[l] - 0.5f * p24a + (1.f/3.f) * p34a - 0.25f * p44a;
            out4b[l] = R4b[l] - 0.5f * p24b + (1.f/3.f) * p34b - 0.25f * p44b;
        }
        float4* d1 = (float4*)(part + base + 584 + tid * 8);
        d1[0] = make_float4(out4a[0], out4a[1], out4a[2], out4a[3]);
        d1[1] = make_float4(out4a[4], out4a[5], out4a[6], out4a[7]);
        float4* d2 = (float4*)(part + base + 584 + pos2 * 8);
        d2[0] = make_float4(out4b[0], out4b[1], out4b[2], out4b[3]);
        d2[1] = make_float4(out4b[4], out4b[5], out4b[6], out4b[7]);
        part[base + 72 + tid]  = R3a - 0.5f * q23a + (1.f/3.f) * s1ia * s1j * s1k;
        part[base + 72 + pos2] = R3b - 0.5f * q23b + (1.f/3.f) * s1ib * s1j * s1k;
        if (tid < 64) part[base + 8 + tid] = R2v - 0.5f * sR[tid >> 3] * sR[tid & 7];
        if (tid < 8)  part[base + tid] = R1v;
    }
}

// ------------------------------------------------ kernel 5: pool over n (grid 8*19)
__global__ __launch_bounds__(256) void pool_reduce_kernel(const float* __restrict__ part,
                                                          float* __restrict__ pooled) {
    int bx = blockIdx.x;
    int b = bx / 19, sl = bx % 19;
    int idx = sl * 256 + threadIdx.x;
    if (idx >= MEM) return;
    float s = 0.f;
    const float* p = part + (size_t)b * 128 * MEM + idx;
#pragma unroll 4
    for (int n = 0; n < 128; n++) s += p[(size_t)n * MEM];
    pooled[b * MEM + idx] = s * (1.f / 128.f);
}

// ------------------------------------------------ kernel 6: gemv -> hpart (no atomics)
__global__ __launch_bounds__(256) void gemv1_kernel(const float* __restrict__ pooled,
                                                    const float* __restrict__ W1,
                                                    float* __restrict__ hpart) {
    int kc = blockIdx.x;
    int tid = threadIdx.x;
    int k0 = kc * 32;
    __shared__ float sp[8][32];
    {
        int b = tid >> 5, k = tid & 31;
        sp[b][k] = (k0 + k < MEM) ? pooled[b * MEM + k0 + k] : 0.f;
    }
    __syncthreads();
    float acc[8];
#pragma unroll
    for (int b = 0; b < 8; b++) acc[b] = 0.f;
    int kend = (k0 + 32 < MEM) ? 32 : (MEM - k0);
    for (int k = 0; k < kend; k++) {
        float wv = W1[(size_t)(k0 + k) * 256 + tid];
#pragma unroll
        for (int b = 0; b < 8; b++) acc[b] += sp[b][k] * wv;
    }
#pragma unroll
    for (int b = 0; b < 8; b++) hpart[(size_t)kc * 2048 + b * 256 + tid] = acc[b];
}

// ------------------------------------------------ kernel 7: reduce hpart + final MLP
__global__ __launch_bounds__(256) void final_kernel(const float* __restrict__ hpart,
                                                    const float* __restrict__ b1,
                                                    const float* __restrict__ W2,
                                                    const float* __restrict__ b2,
                                                    float* __restrict__ outp) {
    int b = blockIdx.x;
    int tid = threadIdx.x;
    float v = 0.f;
    for (int kc = 0; kc < 147; kc++) v += hpart[(size_t)kc * 2048 + b * 256 + tid];
    v += b1[tid];
    v = fmaxf(v, 0.f) * W2[tid];
    __shared__ float sRed[256];
    sRed[tid] = v;
    __syncthreads();
    for (int s = 128; s > 0; s >>= 1) {
        if (tid < s) sRed[tid] += sRed[tid + s];
        __syncthreads();
    }
    if (tid == 0) outp[b] = sRed[0] + b2[0];
}

// ------------------------------------------------ launch
extern "C" void kernel_launch(void* const* d_in, const int* in_sizes, int n_in,
                              void* d_out, int out_size, void* d_ws, size_t ws_size,
                              hipStream_t stream) {
    const float* x  = (const float*)d_in[0];
    const float* W1 = (const float*)d_in[1];
    const float* b1 = (const float*)d_in[2];
    const float* W2 = (const float*)d_in[3];
    const float* b2 = (const float*)d_in[4];
    float* out = (float*)d_out;

    float* ws = (float*)d_ws;
    float* Q      = ws;                            // 1024*MEM: chunk sigs -> in-place cumulatives
    float* P      = Q + (size_t)1024 * MEM;        // 256*MEM: group exclusive prefixes
    float* part   = P + (size_t)256 * MEM;         // 1024*MEM: per-(b,n) log-sigs
    float* pooled = part + (size_t)1024 * MEM;     // 8*MEM
    float* hpart  = pooled + 8 * MEM;              // 147*2048

    chunk_sig_kernel<<<1024, 256, 0, stream>>>(x, Q);
    group_fold_kernel<<<256, 256, 0, stream>>>(Q);
    scan_fused_kernel<<<128, 256, 0, stream>>>(Q, P);
    apply_log_kernel<<<1024, 256, 0, stream>>>(Q, P, part);
    pool_reduce_kernel<<<8 * 19, 256, 0, stream>>>(part, pooled);
    gemv1_kernel<<<147, 256, 0, stream>>>(pooled, W1, hpart);
    final_kernel<<<8, 256, 0, stream>>>(hpart, b1, W2, b2, out);
}

// Round 10
// 141.613 us; speedup vs baseline: 1.0589x; 1.0589x over previous
//
#include <hip/hip_runtime.h>

// BLAMem: truncated tensor-algebra (depth 4, C=8) log-signature memory.
// 5 stream-ordered dispatches. Lessons: no cross-block flag sync (r6), no
// device-scope atomic reductions (r7), stride-9 padded LDS rows (r7), don't
// trade traffic for parallelism (r9). This round: half-groups (2 chunks) give
// the two dominant kernels 2 blocks/CU and half the serial fold chain.

#define MEM   4680   // 8 + 64 + 512 + 4096 (unpadded global layout)
#define HG    64     // half-groups per batch (2 chunks each)
#define TLEN  2048
// Padded LDS signature layout: L1 [0,8), L2 [8,72), L3 rows ij*9+k at 72 (576),
// L4 rows ijk*9+l at 648 (4608). Total 5256 floats.
#define P3OFF 72
#define P4OFF 648
#define SIGSZ 5256

// padded-LDS <- unpadded-global signature row (coalesced reads, conflict-free writes)
__device__ __forceinline__ void load_padded(float* dst, const float* __restrict__ src, int tid) {
    if (tid < 72) dst[tid] = src[tid];
    for (int e = tid; e < 512; e += 256) dst[P3OFF + (e >> 3) * 9 + (e & 7)] = src[72 + e];
    for (int e = tid; e < 4096; e += 256) dst[P4OFF + (e >> 3) * 9 + (e & 7)] = src[584 + e];
}

// Load the 32 per-step increments for half-group (b,h) into sInc[256].
__device__ __forceinline__ void load_inc32(const float* __restrict__ x, int b, int h,
                                           float* sInc, int tid) {
    int s = tid >> 3, c = tid & 7;
    int t = h * 32 + s;
    float v;
    if (c < 7) {
        float cur  = x[(b * TLEN + t) * 7 + c];
        float prev = (t > 0) ? x[(b * TLEN + t - 1) * 7 + c] : 0.f;
        v = cur - prev;
    } else v = (t > 0) ? (1.f / 2047.f) : 0.f;
    sInc[tid] = v;
}

// 16-step closed-form chunk recurrence (per-thread registers).
#define CHUNK_RECUR(dch)                                                            \
    float p1a = 0.f, l2a = 0.f, l3a = 0.f, p1b = 0.f, l2b = 0.f, l3b = 0.f;         \
    float Sa[8], Sb[8];                                                             \
    _Pragma("unroll")                                                               \
    for (int l = 0; l < 8; l++) { Sa[l] = 0.f; Sb[l] = 0.f; }                       \
    _Pragma("unroll")                                                               \
    for (int t = 0; t < 16; t++) {                                                  \
        const float* dr = (dch) + t * 8;                                            \
        float di1 = dr[i1], di2 = dr[i2], dj = dr[j1], dk = dr[k1];                 \
        float ga = l3a + dk * (l2a * 0.5f + dj * (p1a * (1.f/6.f) + di1 * (1.f/24.f))); \
        float gb = l3b + dk * (l2b * 0.5f + dj * (p1b * (1.f/6.f) + di2 * (1.f/24.f))); \
        _Pragma("unroll")                                                           \
        for (int l = 0; l < 8; l++) { float dv = dr[l]; Sa[l] += ga * dv; Sb[l] += gb * dv; } \
        l3a += dk * (l2a + dj * (p1a * 0.5f + di1 * (1.f/6.f)));                    \
        l3b += dk * (l2b + dj * (p1b * 0.5f + di2 * (1.f/6.f)));                    \
        l2a += (p1a + di1 * 0.5f) * dj;                                             \
        l2b += (p1b + di2 * 0.5f) * dj;                                             \
        p1a += di1; p1b += di2;                                                     \
    }

// First chunk: write closed-form sig directly into padded sA (no fold, no zero-init).
__device__ __forceinline__ void chunk_step_first(const float* dch, float* sA, int tid) {
    const int i1 = tid >> 6, j1 = (tid >> 3) & 7, k1 = tid & 7;
    const int row1 = tid >> 3, row2 = row1 + 32;
    const int pos2 = tid + 256, i2 = pos2 >> 6;
    CHUNK_RECUR(dch)
#pragma unroll
    for (int l = 0; l < 8; l++) { sA[P4OFF + tid * 9 + l] = Sa[l]; sA[P4OFF + pos2 * 9 + l] = Sb[l]; }
    sA[P3OFF + row1 * 9 + k1] = l3a;
    sA[P3OFF + row2 * 9 + k1] = l3b;
    if (k1 == 0) { sA[8 + row1] = l2a; sA[8 + row2] = l2b; }
    if ((tid & 63) == 0) { sA[i1] = p1a; sA[i2] = p1b; }
    __syncthreads();
}

// Subsequent chunk: closed form + fold into running padded product sA.
// U scratch: loc3 padded 576 | loc2 64 | loc1 8 = 648 floats.
__device__ __forceinline__ void chunk_step(const float* dch, float* sA, float* U, int tid) {
    float* loc3 = U;
    float* loc2 = U + 576;
    float* loc1 = U + 640;
    const int i1 = tid >> 6, j1 = (tid >> 3) & 7, k1 = tid & 7;
    const int row1 = tid >> 3, row2 = row1 + 32;
    const int jk = tid & 63;
    const int pos2 = tid + 256, i2 = pos2 >> 6;
    CHUNK_RECUR(dch)
    loc3[row1 * 9 + k1] = l3a;
    loc3[row2 * 9 + k1] = l3b;
    if (k1 == 0) { loc2[row1] = l2a; loc2[row2] = l2b; }
    if (jk == 0) { loc1[i1] = p1a; loc1[i2] = p1b; }
    __syncthreads();
    float a1 = sA[i1], a2 = sA[8 + row1], a3 = sA[P3OFF + row1 * 9 + k1];
    float c1_ = sA[i2], c2_ = sA[8 + row2], c3_ = sA[P3OFF + row2 * 9 + k1];
    const float* l3p = &loc3[jk * 9];
    const float* l2p = &loc2[k1 * 8];
    float n4a[8], n4b[8];
#pragma unroll
    for (int l = 0; l < 8; l++) {
        float v3 = l3p[l], v2 = l2p[l], v1 = loc1[l];
        n4a[l] = sA[P4OFF + tid * 9 + l]  + Sa[l] + a1 * v3 + a2 * v2 + a3 * v1;
        n4b[l] = sA[P4OFF + pos2 * 9 + l] + Sb[l] + c1_ * v3 + c2_ * v2 + c3_ * v1;
    }
    float n3a = a3 + l3a + a1 * loc2[jk] + a2 * loc1[k1];
    float n3b = c3_ + l3b + c1_ * loc2[jk] + c2_ * loc1[k1];
    float n2v = 0.f, n1v = 0.f;
    if (tid < 64) n2v = sA[8 + tid] + loc2[tid] + sA[tid >> 3] * loc1[tid & 7];
    if (tid < 8)  n1v = sA[tid] + loc1[tid];
    __syncthreads();
#pragma unroll
    for (int l = 0; l < 8; l++) { sA[P4OFF + tid * 9 + l] = n4a[l]; sA[P4OFF + pos2 * 9 + l] = n4b[l]; }
    sA[P3OFF + row1 * 9 + k1] = n3a;
    sA[P3OFF + row2 * 9 + k1] = n3b;
    if (tid < 64) sA[8 + tid] = n2v;
    if (tid < 8)  sA[tid] = n1v;
    __syncthreads();
}

// ------------------------------------------------ kernel 1: half-group totals (grid 512)
__global__ __launch_bounds__(256) void sig_half_kernel(const float* __restrict__ x,
                                                       float* __restrict__ T) {
    int blk = blockIdx.x;
    int b = blk >> 6, h = blk & 63;
    int tid = threadIdx.x;
    __shared__ __attribute__((aligned(16))) float sInc[256];
    __shared__ __attribute__((aligned(16))) float sA[SIGSZ];
    __shared__ __attribute__((aligned(16))) float U[648];

    load_inc32(x, b, h, sInc, tid);
    __syncthreads();
    chunk_step_first(&sInc[0], sA, tid);
    chunk_step(&sInc[128], sA, U, tid);

    size_t base = (size_t)blk * MEM;
    for (int m = tid; m < MEM; m += 256) {
        float v;
        if (m < 72) v = sA[m];
        else if (m < 584) { int e = m - 72;  v = sA[P3OFF + (e >> 3) * 9 + (e & 7)]; }
        else              { int e = m - 584; v = sA[P4OFF + (e >> 3) * 9 + (e & 7)]; }
        T[base + m] = v;
    }
}

// ------------------------------------------------ kernel 2: cascade scan T -> P (grid 128)
// 8 batches x 16 slices; exclusive ta_mul prefixes of the 64 half-group totals.
__global__ __launch_bounds__(256) void scan_fused_kernel(const float* __restrict__ T,
                                                         float* __restrict__ P) {
    int bx = blockIdx.x;
    int b = bx >> 4, s = bx & 15;
    int tid = threadIdx.x;

    __shared__ float st1[HG][8];
    __shared__ float st2[HG][64];
    __shared__ float st3[HG][32];
    __shared__ float sp1[HG][8];
    __shared__ float sp2[HG][64];
    __shared__ float sp3[HG][32];

    int bBase = b * HG;
    for (int m = tid; m < HG * 8; m += 256) {
        int g = m >> 3, i = m & 7;
        st1[g][i] = T[(size_t)(bBase + g) * MEM + i];
    }
    for (int m = tid; m < HG * 64; m += 256) {
        int g = m >> 6, e = m & 63;
        st2[g][e] = T[(size_t)(bBase + g) * MEM + 8 + e];
    }
    for (int m = tid; m < HG * 32; m += 256) {
        int g = m >> 5, e = m & 31;
        st3[g][e] = T[(size_t)(bBase + g) * MEM + 72 + s * 32 + e];
    }
    __syncthreads();

    if (tid < 64) {
        int i = tid >> 3, k = tid & 7;
        float p1acc = 0.f, p2acc = 0.f;
        for (int g = 0; g < HG; g++) {
            sp2[g][tid] = p2acc;
            if (k == 0) sp1[g][i] = p1acc;
            if (s == 0) {
                size_t prow = (size_t)(bBase + g) * MEM;
                P[prow + 8 + tid] = p2acc;
                if (k == 0) P[prow + i] = p1acc;
            }
            p2acc += st2[g][tid] + p1acc * st1[g][k];
            p1acc += st1[g][i];
        }
    }
    __syncthreads();
    if (tid < 32) {
        int ijk = s * 32 + tid;
        int i = ijk >> 6, jk = ijk & 63, ij = ijk >> 3, k = ijk & 7;
        float acc3 = 0.f;
        for (int g = 0; g < HG; g++) {
            sp3[g][tid] = acc3;
            P[(size_t)(bBase + g) * MEM + 72 + ijk] = acc3;
            acc3 += st3[g][tid] + sp1[g][i] * st2[g][jk] + sp2[g][ij] * st1[g][k];
        }
    }
    __syncthreads();
    {
        int m = s * 256 + tid;
        int i = m >> 9, jkl = m & 511, ij = m >> 6, kl = m & 63, l = m & 7;
        int p3loc = tid >> 3;
        float acc4 = 0.f;
#pragma unroll 4
        for (int g = 0; g < HG; g++) {
            size_t row = (size_t)(bBase + g) * MEM;
            P[row + 584 + m] = acc4;
            acc4 += T[row + 584 + m]
                  + sp1[g][i] * T[row + 72 + jkl]
                  + sp2[g][ij] * st2[g][kl]
                  + sp3[g][p3loc] * st1[g][l];
        }
    }
}

// ------------------------------------------------ kernel 3: recompute 2 chunks + apply + log
// grid 512, block (b,h): for each chunk, R = P[b,h] (x) cum; accumulate ta_log(R).
__global__ __launch_bounds__(256) void apply_log_kernel(const float* __restrict__ x,
                                                        const float* __restrict__ P,
                                                        float* __restrict__ partial) {
    int blk = blockIdx.x;
    int b = blk >> 6, h = blk & 63;
    int tid = threadIdx.x;

    __shared__ __attribute__((aligned(16))) float sInc[256];
    __shared__ __attribute__((aligned(16))) float sA[SIGSZ];
    __shared__ __attribute__((aligned(16))) float sP[SIGSZ];
    __shared__ __attribute__((aligned(16))) float U[648];
    __shared__ __attribute__((aligned(16))) float sR[648];
    __shared__ __attribute__((aligned(16))) float sQ23[576];

    load_inc32(x, b, h, sInc, tid);
    load_padded(sP, P + (size_t)blk * MEM, tid);
    __syncthreads();

    const int i1 = tid >> 6, j1 = (tid >> 3) & 7, k1 = tid & 7;
    const int row1 = tid >> 3, row2 = row1 + 32;
    const int jk = tid & 63;
    const int pos2 = tid + 256, i2 = pos2 >> 6;

    float pool4a[8], pool4b[8];
#pragma unroll
    for (int l = 0; l < 8; l++) { pool4a[l] = 0.f; pool4b[l] = 0.f; }
    float pool3a = 0.f, pool3b = 0.f, pool2 = 0.f, pool1 = 0.f;

    for (int c = 0; c < 2; c++) {
        if (c == 0) chunk_step_first(&sInc[0], sA, tid);
        else        chunk_step(&sInc[128], sA, U, tid);

        float a1 = sP[i1], a2 = sP[8 + row1], a3 = sP[P3OFF + row1 * 9 + k1];
        float c1_ = sP[i2], c2_ = sP[8 + row2], c3_ = sP[P3OFF + row2 * 9 + k1];
        const float* b3p = &sA[P3OFF + jk * 9];
        const float* b2p = &sA[8 + k1 * 8];
        float R4a[8], R4b[8];
#pragma unroll
        for (int l = 0; l < 8; l++) {
            float v3 = b3p[l], v2 = b2p[l], v1 = sA[l];
            R4a[l] = sP[P4OFF + tid * 9 + l]  + sA[P4OFF + tid * 9 + l]  + a1 * v3 + a2 * v2 + a3 * v1;
            R4b[l] = sP[P4OFF + pos2 * 9 + l] + sA[P4OFF + pos2 * 9 + l] + c1_ * v3 + c2_ * v2 + c3_ * v1;
        }
        float R3a = a3 + sA[P3OFF + row1 * 9 + k1] + a1 * sA[8 + jk] + a2 * sA[k1];
        float R3b = c3_ + sA[P3OFF + row2 * 9 + k1] + c1_ * sA[8 + jk] + c2_ * sA[k1];
        float R2v = 0.f, R1v = 0.f;
        if (tid < 64) R2v = sP[8 + tid] + sA[8 + tid] + sP[tid >> 3] * sA[tid & 7];
        if (tid < 8)  R1v = sP[tid] + sA[tid];

        sR[P3OFF + row1 * 9 + k1] = R3a;
        sR[P3OFF + row2 * 9 + k1] = R3b;
        if (tid < 64) sR[8 + tid] = R2v;
        if (tid < 8)  sR[tid] = R1v;
        __syncthreads();

        float q23a = sR[i1] * sR[8 + jk] + sR[8 + row1] * sR[k1];
        float q23b = sR[i2] * sR[8 + jk] + sR[8 + row2] * sR[k1];
        sQ23[row1 * 9 + k1] = q23a;
        sQ23[row2 * 9 + k1] = q23b;
        __syncthreads();

        {
            float s1ia = sR[i1], s1ib = sR[i2], s1j = sR[j1], s1k = sR[k1];
            float s2ija = sR[8 + row1], s2ijb = sR[8 + row2];
            const float* r3p = &sR[P3OFF + jk * 9];
            const float* r2p = &sR[8 + k1 * 8];
            const float* q23p = &sQ23[jk * 9];
#pragma unroll
            for (int l = 0; l < 8; l++) {
                float s1l = sR[l];
                float p22 = s1k * s1l;
                float p24a = s1ia * r3p[l] + s2ija * r2p[l] + R3a * s1l;
                float p24b = s1ib * r3p[l] + s2ijb * r2p[l] + R3b * s1l;
                float p34a = s1ia * q23p[l] + s2ija * p22;
                float p34b = s1ib * q23p[l] + s2ijb * p22;
                float p44a = s1ia * s1j * p22;
                float p44b = s1ib * s1j * p22;
                pool4a[l] += R4a[l] - 0.5f * p24a + (1.f/3.f) * p34a - 0.25f * p44a;
                pool4b[l] += R4b[l] - 0.5f * p24b + (1.f/3.f) * p34b - 0.25f * p44b;
            }
            pool3a += R3a - 0.5f * q23a + (1.f/3.f) * s1ia * s1j * s1k;
            pool3b += R3b - 0.5f * q23b + (1.f/3.f) * s1ib * s1j * s1k;
            if (tid < 64) pool2 += R2v - 0.5f * sR[tid >> 3] * sR[tid & 7];
            if (tid < 8)  pool1 += R1v;
        }
        __syncthreads();   // sR/sQ23 reads done before next iteration overwrites
    }

    {
        float* pb = partial + (size_t)blk * MEM;
        float4* d1 = (float4*)(pb + 584 + tid * 8);
        d1[0] = make_float4(pool4a[0], pool4a[1], pool4a[2], pool4a[3]);
        d1[1] = make_float4(pool4a[4], pool4a[5], pool4a[6], pool4a[7]);
        float4* d2 = (float4*)(pb + 584 + pos2 * 8);
        d2[0] = make_float4(pool4b[0], pool4b[1], pool4b[2], pool4b[3]);
        d2[1] = make_float4(pool4b[4], pool4b[5], pool4b[6], pool4b[7]);
        pb[72 + tid] = pool3a;
        pb[72 + pos2] = pool3b;
        if (tid < 64) pb[8 + tid] = pool2;
        if (tid < 8)  pb[tid] = pool1;
    }
}

// ------------------------------------------------ kernel 4: reduce partials + gemv -> hpart
__global__ __launch_bounds__(256) void gemv1_kernel(const float* __restrict__ partial,
                                                    const float* __restrict__ W1,
                                                    float* __restrict__ hpart) {
    int kc = blockIdx.x;
    int tid = threadIdx.x;
    int k0 = kc * 32;
    __shared__ float sp[8][32];
    {
        int b = tid >> 5, k = tid & 31;
        float sum = 0.f;
        if (k0 + k < MEM) {
#pragma unroll 4
            for (int g = 0; g < HG; g++)
                sum += partial[(size_t)(b * HG + g) * MEM + k0 + k];
        }
        sp[b][k] = sum * (1.f / 128.f);
    }
    __syncthreads();
    float acc[8];
#pragma unroll
    for (int b = 0; b < 8; b++) acc[b] = 0.f;
    int kend = (k0 + 32 < MEM) ? 32 : (MEM - k0);
    for (int k = 0; k < kend; k++) {
        float wv = W1[(size_t)(k0 + k) * 256 + tid];
#pragma unroll
        for (int b = 0; b < 8; b++) acc[b] += sp[b][k] * wv;
    }
#pragma unroll
    for (int b = 0; b < 8; b++) hpart[(size_t)kc * 2048 + b * 256 + tid] = acc[b];
}

// ------------------------------------------------ kernel 5: reduce hpart + final MLP
__global__ __launch_bounds__(256) void final_kernel(const float* __restrict__ hpart,
                                                    const float* __restrict__ b1,
                                                    const float* __restrict__ W2,
                                                    const float* __restrict__ b2,
                                                    float* __restrict__ outp) {
    int b = blockIdx.x;
    int tid = threadIdx.x;
    float v = 0.f;
    for (int kc = 0; kc < 147; kc++) v += hpart[(size_t)kc * 2048 + b * 256 + tid];
    v += b1[tid];
    v = fmaxf(v, 0.f) * W2[tid];
    __shared__ float sRed[256];
    sRed[tid] = v;
    __syncthreads();
    for (int s = 128; s > 0; s >>= 1) {
        if (tid < s) sRed[tid] += sRed[tid + s];
        __syncthreads();
    }
    if (tid == 0) outp[b] = sRed[0] + b2[0];
}

// ------------------------------------------------ launch
extern "C" void kernel_launch(void* const* d_in, const int* in_sizes, int n_in,
                              void* d_out, int out_size, void* d_ws, size_t ws_size,
                              hipStream_t stream) {
    const float* x  = (const float*)d_in[0];
    const float* W1 = (const float*)d_in[1];
    const float* b1 = (const float*)d_in[2];
    const float* W2 = (const float*)d_in[3];
    const float* b2 = (const float*)d_in[4];
    float* out = (float*)d_out;

    float* ws = (float*)d_ws;
    float* T       = ws;                            // 512*MEM (half-group totals)
    float* P       = T + (size_t)512 * MEM;         // 512*MEM (exclusive prefixes)
    float* partial = P + (size_t)512 * MEM;         // 512*MEM (pooled partials)
    float* hpart   = partial + (size_t)512 * MEM;   // 147*2048

    sig_half_kernel<<<512, 256, 0, stream>>>(x, T);
    scan_fused_kernel<<<128, 256, 0, stream>>>(T, P);
    apply_log_kernel<<<512, 256, 0, stream>>>(x, P, partial);
    gemv1_kernel<<<147, 256, 0, stream>>>(partial, W1, hpart);
    final_kernel<<<8, 256, 0, stream>>>(hpart, b1, W2, b2, out);
}